// Round 9
// baseline (283.579 us; speedup 1.0000x reference)
//
#include <hip/hip_runtime.h>
#include <stdint.h>

// ---------------------------------------------------------------------------
// CrossAttention_43061342110469 — algebraic reduction:
// einsum('bvhd,bhqk->bvhd', v, softmax(scores)) == v * L  (softmax rows sum
// to 1; summed over q gives L=2048). So out = 2048*(x @ Wv @ Wo) + const.
//
// R9: gemm_main is now LDS-FREE and BARRIER-FREE. Evidence: R4 (2-barrier)
// and R8 (1-barrier full-dbuf) both pinned at 44 us with all pipes <17% ->
// the LDS-staging+barrier category (GLD16 vmcnt(0) drains at s_barrier,
// 2 waves/SIMD can't cover) is the limiter, not its arrangement.
// Both MFMA fragments load DIRECTLY from global:
//   A-frag: x row-major, lane reads 8 contiguous fp32 -> pack8 in-reg
//   B-frag: Wt pre-transposed [N][K], lane reads 16 contiguous bytes
// Reuse via L1/L2 (A-panel XCD-shared by swizzle; Wt 2MB L2-resident).
// 512-thread blocks (8 waves of 64x32) -> 4 waves/SIMD if VGPR<=128.
// LDS only for the per-wave epilogue transpose (18KB, no barrier).
// wgemm (K1) unchanged from R3 for clean attribution.
// ---------------------------------------------------------------------------

typedef __attribute__((ext_vector_type(8))) short bf16x8;
typedef __attribute__((ext_vector_type(4))) float f32x4;

typedef __attribute__((address_space(1))) void as1_void;
typedef __attribute__((address_space(3))) void as3_void;
#define GLD16(g, s)                                                          \
  __builtin_amdgcn_global_load_lds((as1_void*)(g), (as3_void*)(s), 16, 0, 0)

__device__ __forceinline__ short f2bf(float f) {
  union { float f; uint32_t u; } v; v.f = f;
  uint32_t r = v.u + 0x7FFFu + ((v.u >> 16) & 1u);  // round-to-nearest-even
  return (short)(r >> 16);
}

// pack 8 fp32 -> bf16x8 (+0x8000, take high16 via v_perm)
__device__ __forceinline__ bf16x8 pack8(f32x4 a, f32x4 b) {
  union { f32x4 f; uint32_t u[4]; } x, y;
  x.f = a; y.f = b;
#pragma unroll
  for (int t = 0; t < 4; ++t) x.u[t] += 0x8000u;
#pragma unroll
  for (int t = 0; t < 4; ++t) y.u[t] += 0x8000u;
  union { bf16x8 v; uint32_t u[4]; } o;
  o.u[0] = __builtin_amdgcn_perm(x.u[1], x.u[0], 0x07060302);
  o.u[1] = __builtin_amdgcn_perm(x.u[3], x.u[2], 0x07060302);
  o.u[2] = __builtin_amdgcn_perm(y.u[1], y.u[0], 0x07060302);
  o.u[3] = __builtin_amdgcn_perm(y.u[3], y.u[2], 0x07060302);
  return o.v;
}

// ---- K1: blocks [0,512): Wt = 2048*(Wv@Wo)^T with in-kernel Wo transpose;
//          blocks [512,576): biasc[n] = 2048*sum_k bv[k]*Wo[k,n] + bo[n].
// (unchanged from R3)
__global__ __launch_bounds__(256) void wgemm(
    const float* __restrict__ Wo, const float* __restrict__ Wv,
    const float* __restrict__ bv, const float* __restrict__ bo,
    short* __restrict__ Wt, float* __restrict__ biasc) {
  constexpr int BK = 64, NW = 1024;  // NW = row stride of Wo / Wv / Wt
  __shared__ __align__(16) float Bsf[64 * BK];  // 16 KB fp32 (Wv tile)
  __shared__ __align__(16) float Ts[64 * 36];   //  9 KB fp32 (Wo^T stage)
  const int b = blockIdx.x, tid = threadIdx.x;

  if (b >= 512) {  // ---- bias blocks
    float* red = Bsf;
    const int b3 = b - 512;
    const int nx = tid & 15, ky = tid >> 4;
    const int n = b3 * 16 + nx;
    float s = 0.f;
    for (int k = ky; k < 1024; k += 16)
      s += bv[k] * Wo[(size_t)k * NW + n];
    red[tid] = s;
    __syncthreads();
#pragma unroll
    for (int st = 128; st >= 16; st >>= 1) {
      if (tid < st) red[tid] += red[tid + st];
      __syncthreads();
    }
    if (ky == 0) biasc[n] = 2048.0f * red[nx] + bo[n];
    return;
  }

  // ---- gemm blocks: bm = n-tile (Wo cols), bn = k-tile (Wv rows)
  const int lane = tid & 63, wave = tid >> 6;
  const int bm = (b >> 4) * 32, bn = (b & 15) * 64;
  const int wm = (wave & 1) * 16, wn = (wave >> 1) * 32;
  const int l15 = lane & 15, quad = lane >> 4;

  f32x4 acc[2];
  acc[0] = (f32x4){0.f, 0.f, 0.f, 0.f};
  acc[1] = (f32x4){0.f, 0.f, 0.f, 0.f};

  // B (fp32): 64 rows x 16 chunks(16B) = 1024 chunks, 4/thread, XOR swizzle
  const int br = tid >> 4, bc4 = (tid & 15) ^ (br & 7);
  const float* pb = Wv + (size_t)(bn + br) * NW + bc4 * 4;
  float* lb = Bsf + tid * 4;

  // A (Wo transpose-stage): rows j = tid>>3 (+32), cols bm + (tid&7)*4
  const int ajr = tid >> 3, ac4 = (tid & 7) * 4;
  const float* pa = Wo + (size_t)ajr * NW + bm + ac4;

  for (int kt = 0; kt < 1024; kt += BK) {
    float4 va = *(const float4*)(pa);
    float4 vb = *(const float4*)(pa + 32 * (size_t)NW);
    pa += (size_t)BK * NW;
#pragma unroll
    for (int s = 0; s < 4; ++s) GLD16(pb + (size_t)(16 * s) * NW, lb + 1024 * s);
    pb += BK;
    *(float4*)(Ts + ajr * 36 + ac4) = va;
    *(float4*)(Ts + (ajr + 32) * 36 + ac4) = vb;
    __syncthreads();
#pragma unroll
    for (int kk = 0; kk < 2; ++kk) {
      // A-frag: n-row = wm+l15, j = (kk*4+quad)*8 + e  (column read of Ts)
      const float* tsp = Ts + ((kk * 4 + quad) * 8) * 36 + wm + l15;
      float av[8];
#pragma unroll
      for (int e = 0; e < 8; ++e) av[e] = tsp[e * 36];
      bf16x8 af = pack8((f32x4){av[0], av[1], av[2], av[3]},
                        (f32x4){av[4], av[5], av[6], av[7]});
#pragma unroll
      for (int j = 0; j < 2; ++j) {
        const int rn = wn + j * 16 + l15;
        const int c4 = kk * 8 + quad * 2;
        f32x4 u0 = *(const f32x4*)(Bsf + (rn * 16 + (c4 ^ (rn & 7))) * 4);
        f32x4 u1 = *(const f32x4*)(Bsf + (rn * 16 + ((c4 + 1) ^ (rn & 7))) * 4);
        acc[j] = __builtin_amdgcn_mfma_f32_16x16x32_bf16(af, pack8(u0, u1),
                                                         acc[j], 0, 0, 0);
      }
    }
    __syncthreads();
  }
#pragma unroll
  for (int j = 0; j < 2; ++j) {
    const int col = bn + wn + j * 16 + l15;   // k-dim
    const int row0 = bm + wm + quad * 4;      // n-dim
#pragma unroll
    for (int r = 0; r < 4; ++r)
      Wt[(size_t)(row0 + r) * NW + col] = f2bf(2048.f * acc[j][r]);
  }
}

// ---- K2: out = x @ Wt^T + biasc; 128x128 tile, LDS-free, barrier-free -----
// grid 512 = 64 M-tiles x 8 N-tiles; bm = b&63 -> the 8 N-tiles of one
// x-panel share XCD (b%8) -> panel L2-resident. 512 threads = 8 waves of
// 64x32 (wm 2x64, wn 4x32). Per K-step(32)/wave: 8 A-dwordx4 + 2 B-b128
// loads + 4 pack8 + 8 MFMA, zero DS ops, zero barriers -> compiler
// pipelines loads across iterations freely.
__global__ __launch_bounds__(512) void gemm_main(
    const float* __restrict__ X, const short* __restrict__ Bt,
    const float* __restrict__ bias, float* __restrict__ Out,
    int M, int N, int K) {
  __shared__ __align__(16) float T[8 * 576];  // epilogue only (per-wave 16x36)
  const int tid = threadIdx.x, lane = tid & 63, wave = tid >> 6;
  const int b = blockIdx.x;
  const int bm = (b & 63) * 128;
  const int bn = (b >> 6) * 128;
  const int wm = (wave & 1) * 64, wn = (wave >> 1) * 32;
  const int l15 = lane & 15, quad = lane >> 4;

  f32x4 acc[4][2];
#pragma unroll
  for (int i = 0; i < 4; ++i)
#pragma unroll
    for (int j = 0; j < 2; ++j) acc[i][j] = (f32x4){0.f, 0.f, 0.f, 0.f};

  // per-lane fragment bases: A row = bm+wm+i*16+l15, k-chunk = quad*8
  const float* pa = X + (size_t)(bm + wm + l15) * K + quad * 8;
  // B rows = bn+wn+j*16+l15, same k-chunk
  const short* pb0 = Bt + (size_t)(bn + wn + l15) * K + quad * 8;
  const short* pb1 = pb0 + 16 * (size_t)K;

#pragma unroll 4
  for (int kt = 0; kt < 1024; kt += 32) {
    bf16x8 af0, af1, af2, af3, bf0, bf1;
    {
      const float* p = pa + kt;
      float4 u0 = *(const float4*)(p), u1 = *(const float4*)(p + 4);
      af0 = pack8((f32x4){u0.x, u0.y, u0.z, u0.w},
                  (f32x4){u1.x, u1.y, u1.z, u1.w});
    }
    {
      const float* p = pa + 16 * (size_t)K + kt;
      float4 u0 = *(const float4*)(p), u1 = *(const float4*)(p + 4);
      af1 = pack8((f32x4){u0.x, u0.y, u0.z, u0.w},
                  (f32x4){u1.x, u1.y, u1.z, u1.w});
    }
    {
      const float* p = pa + 32 * (size_t)K + kt;
      float4 u0 = *(const float4*)(p), u1 = *(const float4*)(p + 4);
      af2 = pack8((f32x4){u0.x, u0.y, u0.z, u0.w},
                  (f32x4){u1.x, u1.y, u1.z, u1.w});
    }
    {
      const float* p = pa + 48 * (size_t)K + kt;
      float4 u0 = *(const float4*)(p), u1 = *(const float4*)(p + 4);
      af3 = pack8((f32x4){u0.x, u0.y, u0.z, u0.w},
                  (f32x4){u1.x, u1.y, u1.z, u1.w});
    }
    bf0 = *(const bf16x8*)(pb0 + kt);
    bf1 = *(const bf16x8*)(pb1 + kt);

    acc[0][0] = __builtin_amdgcn_mfma_f32_16x16x32_bf16(af0, bf0, acc[0][0], 0, 0, 0);
    acc[0][1] = __builtin_amdgcn_mfma_f32_16x16x32_bf16(af0, bf1, acc[0][1], 0, 0, 0);
    acc[1][0] = __builtin_amdgcn_mfma_f32_16x16x32_bf16(af1, bf0, acc[1][0], 0, 0, 0);
    acc[1][1] = __builtin_amdgcn_mfma_f32_16x16x32_bf16(af1, bf1, acc[1][1], 0, 0, 0);
    acc[2][0] = __builtin_amdgcn_mfma_f32_16x16x32_bf16(af2, bf0, acc[2][0], 0, 0, 0);
    acc[2][1] = __builtin_amdgcn_mfma_f32_16x16x32_bf16(af2, bf1, acc[2][1], 0, 0, 0);
    acc[3][0] = __builtin_amdgcn_mfma_f32_16x16x32_bf16(af3, bf0, acc[3][0], 0, 0, 0);
    acc[3][1] = __builtin_amdgcn_mfma_f32_16x16x32_bf16(af3, bf1, acc[3][1], 0, 0, 0);
  }

  // epilogue: MFMA C layout (col=l15, row=quad*4+r) -> per-wave LDS tile
  // (16 x 32 used, stride 36) -> full-line float4 stores (same-wave ordering
  // only; no barrier needed).
  float* Tw = T + wave * 576;
#pragma unroll
  for (int i = 0; i < 4; ++i) {
#pragma unroll
    for (int j = 0; j < 2; ++j) {
      const float bb = bias[bn + wn + j * 16 + l15];
#pragma unroll
      for (int r = 0; r < 4; ++r)
        Tw[(quad * 4 + r) * 36 + j * 16 + l15] = acc[i][j][r] + bb;
    }
#pragma unroll
    for (int c = 0; c < 2; ++c) {
      const int row = (lane >> 3) + 8 * c;
      f32x4 v = *(const f32x4*)(Tw + row * 36 + (lane & 7) * 4);
      *(f32x4*)(Out + (size_t)(bm + wm + i * 16 + row) * N + bn + wn +
                (lane & 7) * 4) = v;
    }
  }
}

extern "C" void kernel_launch(void* const* d_in, const int* in_sizes, int n_in,
                              void* d_out, int out_size, void* d_ws,
                              size_t ws_size, hipStream_t stream) {
  // setup_inputs order: x, encoder_x, Wq, bq, Wk, bk, Wv, bv, Wo, bo
  const float* x  = (const float*)d_in[0];
  const float* Wv = (const float*)d_in[6];
  const float* bv = (const float*)d_in[7];
  const float* Wo = (const float*)d_in[8];
  const float* bo = (const float*)d_in[9];
  float* out = (float*)d_out;

  constexpr int D = 1024, NO = 1024;  // NO = H*QKV
  constexpr int M = 8192;             // B*L

  char* ws = (char*)d_ws;
  short* wt_bf = (short*)(ws);              // 2 MB: 2048*(Wv@Wo)^T bf16
  float* biasc = (float*)(ws + (2u << 20)); // 4 KB: fused bias

  wgemm<<<576, 256, 0, stream>>>(Wo, Wv, bv, bo, wt_bf, biasc);
  gemm_main<<<(M / 128) * (NO / 128), 512, 0, stream>>>(
      x, wt_bf, biasc, out, M, NO, D);
}

// Round 10
// 156.749 us; speedup vs baseline: 1.8091x; 1.8091x over previous
//
#include <hip/hip_runtime.h>
#include <stdint.h>

// ---------------------------------------------------------------------------
// CrossAttention_43061342110469 — algebraic reduction:
// einsum('bvhd,bhqk->bvhd', v, softmax(scores)) == v * L  (softmax rows sum
// to 1; summed over q gives L=2048). So out = 2048*(x @ Wv @ Wo) + const.
//
// R10: revert to the PROVEN LDS-broadcast category. R9 (no LDS) showed
// per-lane global fragment loads are L1/L2-port-bound (164us); R4/R8 fp32-A
// reg-staging overflows per-XCD L2 (6MB set) -> 44us. Fix: cast x->bf16
// once (overlapped with wgemm), gemm_main = R1/R2-verified 128x128
// both-operand-GLD16 m97 structure. Per-XCD set: 8 bf16 panels (2MB) +
// Wt (2MB) = 4MB = exact L2 fit; no pack8 in main loop.
//   K1 mid : [0,512) wgemm (R3 verbatim), [512,576) bias, [576,4672) cast.
//   K2 gemm_main: x_bf @ Wt^T + biasc, both GLD16, 2-barrier loop.
// ---------------------------------------------------------------------------

typedef __attribute__((ext_vector_type(8))) short bf16x8;
typedef __attribute__((ext_vector_type(4))) float f32x4;

typedef __attribute__((address_space(1))) void as1_void;
typedef __attribute__((address_space(3))) void as3_void;
#define GLD16(g, s)                                                          \
  __builtin_amdgcn_global_load_lds((as1_void*)(g), (as3_void*)(s), 16, 0, 0)

__device__ __forceinline__ short f2bf(float f) {
  union { float f; uint32_t u; } v; v.f = f;
  uint32_t r = v.u + 0x7FFFu + ((v.u >> 16) & 1u);  // round-to-nearest-even
  return (short)(r >> 16);
}

// pack 8 fp32 -> bf16x8 (+0x8000, take high16 via v_perm)
__device__ __forceinline__ bf16x8 pack8(f32x4 a, f32x4 b) {
  union { f32x4 f; uint32_t u[4]; } x, y;
  x.f = a; y.f = b;
#pragma unroll
  for (int t = 0; t < 4; ++t) x.u[t] += 0x8000u;
#pragma unroll
  for (int t = 0; t < 4; ++t) y.u[t] += 0x8000u;
  union { bf16x8 v; uint32_t u[4]; } o;
  o.u[0] = __builtin_amdgcn_perm(x.u[1], x.u[0], 0x07060302);
  o.u[1] = __builtin_amdgcn_perm(x.u[3], x.u[2], 0x07060302);
  o.u[2] = __builtin_amdgcn_perm(y.u[1], y.u[0], 0x07060302);
  o.u[3] = __builtin_amdgcn_perm(y.u[3], y.u[2], 0x07060302);
  return o.v;
}

// ---- K1: [0,512) Wt = 2048*(Wv@Wo)^T (in-kernel Wo transpose, R3 verbatim);
//          [512,576) biasc; [576,4672) cast x fp32->bf16 (overlaps wgemm). --
__global__ __launch_bounds__(256) void mid(
    const float* __restrict__ Wo, const float* __restrict__ Wv,
    const float* __restrict__ bv, const float* __restrict__ bo,
    const float* __restrict__ x, short* __restrict__ x_bf,
    short* __restrict__ Wt, float* __restrict__ biasc) {
  constexpr int BK = 64, NW = 1024;
  __shared__ __align__(16) float Bsf[64 * BK];  // 16 KB fp32 (Wv tile)
  __shared__ __align__(16) float Ts[64 * 36];   //  9 KB fp32 (Wo^T stage)
  const int b = blockIdx.x, tid = threadIdx.x;

  if (b >= 576) {  // ---- cast x: fp32 -> bf16, 8 elems/thread
    const int i = (b - 576) * 256 + tid;
    const float4* p = (const float4*)x;
    float4 a = p[2 * (size_t)i], c = p[2 * (size_t)i + 1];
    *(bf16x8*)(x_bf + 8 * (size_t)i) =
        pack8((f32x4){a.x, a.y, a.z, a.w}, (f32x4){c.x, c.y, c.z, c.w});
    return;
  }

  if (b >= 512) {  // ---- bias blocks
    float* red = Bsf;
    const int b3 = b - 512;
    const int nx = tid & 15, ky = tid >> 4;
    const int n = b3 * 16 + nx;
    float s = 0.f;
    for (int k = ky; k < 1024; k += 16)
      s += bv[k] * Wo[(size_t)k * NW + n];
    red[tid] = s;
    __syncthreads();
#pragma unroll
    for (int st = 128; st >= 16; st >>= 1) {
      if (tid < st) red[tid] += red[tid + st];
      __syncthreads();
    }
    if (ky == 0) biasc[n] = 2048.0f * red[nx] + bo[n];
    return;
  }

  // ---- gemm blocks: bm = n-tile (Wo cols), bn = k-tile (Wv rows)
  const int lane = tid & 63, wave = tid >> 6;
  const int bm = (b >> 4) * 32, bn = (b & 15) * 64;
  const int wm = (wave & 1) * 16, wn = (wave >> 1) * 32;
  const int l15 = lane & 15, quad = lane >> 4;

  f32x4 acc[2];
  acc[0] = (f32x4){0.f, 0.f, 0.f, 0.f};
  acc[1] = (f32x4){0.f, 0.f, 0.f, 0.f};

  const int br = tid >> 4, bc4 = (tid & 15) ^ (br & 7);
  const float* pb = Wv + (size_t)(bn + br) * NW + bc4 * 4;
  float* lb = Bsf + tid * 4;

  const int ajr = tid >> 3, ac4 = (tid & 7) * 4;
  const float* pa = Wo + (size_t)ajr * NW + bm + ac4;

  for (int kt = 0; kt < 1024; kt += BK) {
    float4 va = *(const float4*)(pa);
    float4 vb = *(const float4*)(pa + 32 * (size_t)NW);
    pa += (size_t)BK * NW;
#pragma unroll
    for (int s = 0; s < 4; ++s) GLD16(pb + (size_t)(16 * s) * NW, lb + 1024 * s);
    pb += BK;
    *(float4*)(Ts + ajr * 36 + ac4) = va;
    *(float4*)(Ts + (ajr + 32) * 36 + ac4) = vb;
    __syncthreads();
#pragma unroll
    for (int kk = 0; kk < 2; ++kk) {
      const float* tsp = Ts + ((kk * 4 + quad) * 8) * 36 + wm + l15;
      float av[8];
#pragma unroll
      for (int e = 0; e < 8; ++e) av[e] = tsp[e * 36];
      bf16x8 af = pack8((f32x4){av[0], av[1], av[2], av[3]},
                        (f32x4){av[4], av[5], av[6], av[7]});
#pragma unroll
      for (int j = 0; j < 2; ++j) {
        const int rn = wn + j * 16 + l15;
        const int c4 = kk * 8 + quad * 2;
        f32x4 u0 = *(const f32x4*)(Bsf + (rn * 16 + (c4 ^ (rn & 7))) * 4);
        f32x4 u1 = *(const f32x4*)(Bsf + (rn * 16 + ((c4 + 1) ^ (rn & 7))) * 4);
        acc[j] = __builtin_amdgcn_mfma_f32_16x16x32_bf16(af, pack8(u0, u1),
                                                         acc[j], 0, 0, 0);
      }
    }
    __syncthreads();
  }
#pragma unroll
  for (int j = 0; j < 2; ++j) {
    const int col = bn + wn + j * 16 + l15;   // k-dim
    const int row0 = bm + wm + quad * 4;      // n-dim
#pragma unroll
    for (int r = 0; r < 4; ++r)
      Wt[(size_t)(row0 + r) * NW + col] = f2bf(2048.f * acc[j][r]);
  }
}

// ---- K2: out = x_bf @ Wt^T + biasc; 128x128, both GLD16 (R1/R2-verified) --
// grid 512 = 64 M-tiles x 8 N-tiles; bm = b&63 -> the 8 N-tiles of one
// x-panel share XCD (b%8); per-XCD L2 set = 8x256KB bf16 panels + 2MB Wt
// = 4MB (fits). Per K-step/wave: 8 ds_read_b128 + 32 MFMA (m97 ratio).
__global__ __launch_bounds__(256) void gemm_main(
    const short* __restrict__ A, const short* __restrict__ Bt,
    const float* __restrict__ bias, float* __restrict__ Out,
    int M, int N, int K) {
  constexpr int BK = 64;
  __shared__ __align__(16) char smem[32768];  // As 16K + Bs 16K; epilogue T
  short* As = (short*)smem;
  short* Bs = (short*)(smem + 16384);
  const int tid = threadIdx.x, lane = tid & 63, wave = tid >> 6;
  const int b = blockIdx.x;
  const int bm = (b & 63) * 128;
  const int bn = (b >> 6) * 128;
  const int wm = (wave & 1) * 64, wn = (wave >> 1) * 64;
  const int l15 = lane & 15, quad = lane >> 4;

  f32x4 acc[4][4];
#pragma unroll
  for (int i = 0; i < 4; ++i)
#pragma unroll
    for (int j = 0; j < 4; ++j) acc[i][j] = (f32x4){0.f, 0.f, 0.f, 0.f};

  // staging with XOR chunk swizzle (LDS[row][c8] = global [row][c8^(row&7)])
  const int srow = tid >> 3, sc8 = (tid & 7) ^ (srow & 7);
  const short* pa = A + (size_t)(bm + srow) * K + sc8 * 8;
  const short* pb = Bt + (size_t)(bn + srow) * K + sc8 * 8;
  short* la = As + tid * 8;
  short* lb = Bs + tid * 8;

  for (int kt = 0; kt < K; kt += BK) {
#pragma unroll
    for (int s = 0; s < 4; ++s) GLD16(pa + (size_t)(32 * s) * K, la + 2048 * s);
#pragma unroll
    for (int s = 0; s < 4; ++s) GLD16(pb + (size_t)(32 * s) * K, lb + 2048 * s);
    pa += BK; pb += BK;
    __syncthreads();
#pragma unroll
    for (int kk = 0; kk < 2; ++kk) {
      bf16x8 af[4], bfr[4];
#pragma unroll
      for (int i = 0; i < 4; ++i) {
        const int r = wm + i * 16 + l15;
        af[i] = *(const bf16x8*)(As + r * BK + ((kk * 4 + quad) ^ (r & 7)) * 8);
      }
#pragma unroll
      for (int j = 0; j < 4; ++j) {
        const int r = wn + j * 16 + l15;
        bfr[j] = *(const bf16x8*)(Bs + r * BK + ((kk * 4 + quad) ^ (r & 7)) * 8);
      }
#pragma unroll
      for (int i = 0; i < 4; ++i)
#pragma unroll
        for (int j = 0; j < 4; ++j)
          acc[i][j] = __builtin_amdgcn_mfma_f32_16x16x32_bf16(
              af[i], bfr[j], acc[i][j], 0, 0, 0);
    }
    __syncthreads();
  }

  // epilogue: MFMA C layout (col=l15, row=quad*4+r) -> per-wave LDS tile
  // (16 x 64, stride 68) -> full-line float4 stores. Same-wave ordering only.
  float* T = (float*)smem + wave * 1088;  // 16 rows x 68 stride
#pragma unroll
  for (int i = 0; i < 4; ++i) {
#pragma unroll
    for (int j = 0; j < 4; ++j) {
      const float bb = bias[bn + wn + j * 16 + l15];
#pragma unroll
      for (int r = 0; r < 4; ++r)
        T[(quad * 4 + r) * 68 + j * 16 + l15] = acc[i][j][r] + bb;
    }
#pragma unroll
    for (int p = 0; p < 4; ++p) {
      const int row = (lane >> 4) + 4 * p;
      const int ch = lane & 15;
      f32x4 v = *(const f32x4*)(T + row * 68 + ch * 4);
      *(f32x4*)(Out + (size_t)(bm + wm + i * 16 + row) * N + bn + wn +
                ch * 4) = v;
    }
  }
}

extern "C" void kernel_launch(void* const* d_in, const int* in_sizes, int n_in,
                              void* d_out, int out_size, void* d_ws,
                              size_t ws_size, hipStream_t stream) {
  // setup_inputs order: x, encoder_x, Wq, bq, Wk, bk, Wv, bv, Wo, bo
  const float* x  = (const float*)d_in[0];
  const float* Wv = (const float*)d_in[6];
  const float* bv = (const float*)d_in[7];
  const float* Wo = (const float*)d_in[8];
  const float* bo = (const float*)d_in[9];
  float* out = (float*)d_out;

  constexpr int D = 1024, NO = 1024;  // NO = H*QKV
  constexpr int M = 8192;             // B*L

  char* ws = (char*)d_ws;
  short* x_bf  = (short*)(ws);                  // 16 MB: x as bf16
  short* wt_bf = (short*)(ws + (16u << 20));    //  2 MB: 2048*(Wv@Wo)^T bf16
  float* biasc = (float*)(ws + (18u << 20));    //  4 KB: fused bias

  mid<<<4672, 256, 0, stream>>>(Wo, Wv, bv, bo, x, x_bf, wt_bf, biasc);
  gemm_main<<<(M / 128) * (NO / 128), 256, 0, stream>>>(
      x_bf, wt_bf, biasc, out, M, NO, D);
}

// Round 11
// 153.866 us; speedup vs baseline: 1.8430x; 1.0187x over previous
//
#include <hip/hip_runtime.h>
#include <stdint.h>

// ---------------------------------------------------------------------------
// CrossAttention_43061342110469 — algebraic reduction:
// einsum('bvhd,bhqk->bvhd', v, softmax(scores)) == v * L  (softmax rows sum
// to 1; summed over q gives L=2048). So out = 2048*(x @ Wv @ Wo) + const.
//
// R11: gemm_main 1-phase -> 2-phase (T3 minimum recipe): LDS double-buffer
// (As0/Bs0/As1/Bs1, 64KB, still 2 blocks/CU), STAGE(t+1) issued BEFORE
// COMPUTE(t), ONE barrier/iter -> the barrier's vmcnt(0) drain lands after
// ~500cy of MFMA+ds_read instead of right after issue. R8 validated this
// even/odd skeleton; its slowness was reg-staged fp32 A (L2 overflow +
// pack VALU), both fixed in R10 (bf16 A via GLD16, 4MB/XCD L2 fit).
//   K1 mid : [0,512) wgemm, [512,576) bias, [576,4672) cast (R10 verbatim).
//   K2 gemm_main: x_bf @ Wt^T + biasc, both GLD16, 2-phase dbuf.
// ---------------------------------------------------------------------------

typedef __attribute__((ext_vector_type(8))) short bf16x8;
typedef __attribute__((ext_vector_type(4))) float f32x4;

typedef __attribute__((address_space(1))) void as1_void;
typedef __attribute__((address_space(3))) void as3_void;
#define GLD16(g, s)                                                          \
  __builtin_amdgcn_global_load_lds((as1_void*)(g), (as3_void*)(s), 16, 0, 0)

__device__ __forceinline__ short f2bf(float f) {
  union { float f; uint32_t u; } v; v.f = f;
  uint32_t r = v.u + 0x7FFFu + ((v.u >> 16) & 1u);  // round-to-nearest-even
  return (short)(r >> 16);
}

// pack 8 fp32 -> bf16x8 (+0x8000, take high16 via v_perm)
__device__ __forceinline__ bf16x8 pack8(f32x4 a, f32x4 b) {
  union { f32x4 f; uint32_t u[4]; } x, y;
  x.f = a; y.f = b;
#pragma unroll
  for (int t = 0; t < 4; ++t) x.u[t] += 0x8000u;
#pragma unroll
  for (int t = 0; t < 4; ++t) y.u[t] += 0x8000u;
  union { bf16x8 v; uint32_t u[4]; } o;
  o.u[0] = __builtin_amdgcn_perm(x.u[1], x.u[0], 0x07060302);
  o.u[1] = __builtin_amdgcn_perm(x.u[3], x.u[2], 0x07060302);
  o.u[2] = __builtin_amdgcn_perm(y.u[1], y.u[0], 0x07060302);
  o.u[3] = __builtin_amdgcn_perm(y.u[3], y.u[2], 0x07060302);
  return o.v;
}

// ---- K1: [0,512) Wt = 2048*(Wv@Wo)^T (in-kernel Wo transpose);
//          [512,576) biasc; [576,4672) cast x fp32->bf16 (overlaps wgemm). --
__global__ __launch_bounds__(256) void mid(
    const float* __restrict__ Wo, const float* __restrict__ Wv,
    const float* __restrict__ bv, const float* __restrict__ bo,
    const float* __restrict__ x, short* __restrict__ x_bf,
    short* __restrict__ Wt, float* __restrict__ biasc) {
  constexpr int BK = 64, NW = 1024;
  __shared__ __align__(16) float Bsf[64 * BK];  // 16 KB fp32 (Wv tile)
  __shared__ __align__(16) float Ts[64 * 36];   //  9 KB fp32 (Wo^T stage)
  const int b = blockIdx.x, tid = threadIdx.x;

  if (b >= 576) {  // ---- cast x: fp32 -> bf16, 8 elems/thread
    const int i = (b - 576) * 256 + tid;
    const float4* p = (const float4*)x;
    float4 a = p[2 * (size_t)i], c = p[2 * (size_t)i + 1];
    *(bf16x8*)(x_bf + 8 * (size_t)i) =
        pack8((f32x4){a.x, a.y, a.z, a.w}, (f32x4){c.x, c.y, c.z, c.w});
    return;
  }

  if (b >= 512) {  // ---- bias blocks
    float* red = Bsf;
    const int b3 = b - 512;
    const int nx = tid & 15, ky = tid >> 4;
    const int n = b3 * 16 + nx;
    float s = 0.f;
    for (int k = ky; k < 1024; k += 16)
      s += bv[k] * Wo[(size_t)k * NW + n];
    red[tid] = s;
    __syncthreads();
#pragma unroll
    for (int st = 128; st >= 16; st >>= 1) {
      if (tid < st) red[tid] += red[tid + st];
      __syncthreads();
    }
    if (ky == 0) biasc[n] = 2048.0f * red[nx] + bo[n];
    return;
  }

  // ---- gemm blocks: bm = n-tile (Wo cols), bn = k-tile (Wv rows)
  const int lane = tid & 63, wave = tid >> 6;
  const int bm = (b >> 4) * 32, bn = (b & 15) * 64;
  const int wm = (wave & 1) * 16, wn = (wave >> 1) * 32;
  const int l15 = lane & 15, quad = lane >> 4;

  f32x4 acc[2];
  acc[0] = (f32x4){0.f, 0.f, 0.f, 0.f};
  acc[1] = (f32x4){0.f, 0.f, 0.f, 0.f};

  const int br = tid >> 4, bc4 = (tid & 15) ^ (br & 7);
  const float* pb = Wv + (size_t)(bn + br) * NW + bc4 * 4;
  float* lb = Bsf + tid * 4;

  const int ajr = tid >> 3, ac4 = (tid & 7) * 4;
  const float* pa = Wo + (size_t)ajr * NW + bm + ac4;

  for (int kt = 0; kt < 1024; kt += BK) {
    float4 va = *(const float4*)(pa);
    float4 vb = *(const float4*)(pa + 32 * (size_t)NW);
    pa += (size_t)BK * NW;
#pragma unroll
    for (int s = 0; s < 4; ++s) GLD16(pb + (size_t)(16 * s) * NW, lb + 1024 * s);
    pb += BK;
    *(float4*)(Ts + ajr * 36 + ac4) = va;
    *(float4*)(Ts + (ajr + 32) * 36 + ac4) = vb;
    __syncthreads();
#pragma unroll
    for (int kk = 0; kk < 2; ++kk) {
      const float* tsp = Ts + ((kk * 4 + quad) * 8) * 36 + wm + l15;
      float av[8];
#pragma unroll
      for (int e = 0; e < 8; ++e) av[e] = tsp[e * 36];
      bf16x8 af = pack8((f32x4){av[0], av[1], av[2], av[3]},
                        (f32x4){av[4], av[5], av[6], av[7]});
#pragma unroll
      for (int j = 0; j < 2; ++j) {
        const int rn = wn + j * 16 + l15;
        const int c4 = kk * 8 + quad * 2;
        f32x4 u0 = *(const f32x4*)(Bsf + (rn * 16 + (c4 ^ (rn & 7))) * 4);
        f32x4 u1 = *(const f32x4*)(Bsf + (rn * 16 + ((c4 + 1) ^ (rn & 7))) * 4);
        acc[j] = __builtin_amdgcn_mfma_f32_16x16x32_bf16(af, pack8(u0, u1),
                                                         acc[j], 0, 0, 0);
      }
    }
    __syncthreads();
  }
#pragma unroll
  for (int j = 0; j < 2; ++j) {
    const int col = bn + wn + j * 16 + l15;   // k-dim
    const int row0 = bm + wm + quad * 4;      // n-dim
#pragma unroll
    for (int r = 0; r < 4; ++r)
      Wt[(size_t)(row0 + r) * NW + col] = f2bf(2048.f * acc[j][r]);
  }
}

// ---- K2: out = x_bf @ Wt^T + biasc; 128x128, both GLD16, 2-phase dbuf -----
// grid 512 = 64 M-tiles x 8 N-tiles; bm = b&63 -> the 8 N-tiles of one
// x-panel share XCD (b%8); per-XCD L2 set = 8x256KB panels + 2MB Wt = 4MB.
// Per iter: STAGE(t+1) -> other buffer (8 GLD16), COMPUTE(t) (8 ds_read_b128
// + 32 MFMA/wave), ONE barrier (its vmcnt(0) drain sits after compute).
__global__ __launch_bounds__(256) void gemm_main(
    const short* __restrict__ A, const short* __restrict__ Bt,
    const float* __restrict__ bias, float* __restrict__ Out,
    int M, int N, int K) {
  constexpr int BK = 64;
  __shared__ __align__(16) char smem[65536];  // As0,Bs0,As1,Bs1 (16K each)
  short* As0 = (short*)smem;
  short* Bs0 = (short*)(smem + 16384);
  short* As1 = (short*)(smem + 32768);
  short* Bs1 = (short*)(smem + 49152);
  const int tid = threadIdx.x, lane = tid & 63, wave = tid >> 6;
  const int b = blockIdx.x;
  const int bm = (b & 63) * 128;
  const int bn = (b >> 6) * 128;
  const int wm = (wave & 1) * 64, wn = (wave >> 1) * 64;
  const int l15 = lane & 15, quad = lane >> 4;

  f32x4 acc[4][4];
#pragma unroll
  for (int i = 0; i < 4; ++i)
#pragma unroll
    for (int j = 0; j < 4; ++j) acc[i][j] = (f32x4){0.f, 0.f, 0.f, 0.f};

  // staging with XOR chunk swizzle (LDS[row][c8] = global [row][c8^(row&7)])
  const int srow = tid >> 3, sc8 = (tid & 7) ^ (srow & 7);
  const short* pa = A + (size_t)(bm + srow) * K + sc8 * 8;
  const short* pb = Bt + (size_t)(bn + srow) * K + sc8 * 8;

#define STAGE(Asx, Bsx, kt)                                                  \
  {                                                                          \
    _Pragma("unroll") for (int s = 0; s < 4; ++s)                            \
        GLD16(pa + (size_t)(32 * s) * K + (kt), (Asx) + tid * 8 + 2048 * s); \
    _Pragma("unroll") for (int s = 0; s < 4; ++s)                            \
        GLD16(pb + (size_t)(32 * s) * K + (kt), (Bsx) + tid * 8 + 2048 * s); \
  }
#define COMPUTE(Asx, Bsx)                                                    \
  {                                                                          \
    _Pragma("unroll") for (int kk = 0; kk < 2; ++kk) {                       \
      bf16x8 af[4], bfr[4];                                                  \
      _Pragma("unroll") for (int i = 0; i < 4; ++i) {                        \
        const int r = wm + i * 16 + l15;                                     \
        af[i] = *(const bf16x8*)((Asx) + r * BK +                            \
                                 ((kk * 4 + quad) ^ (r & 7)) * 8);           \
      }                                                                      \
      _Pragma("unroll") for (int j = 0; j < 4; ++j) {                        \
        const int r = wn + j * 16 + l15;                                     \
        bfr[j] = *(const bf16x8*)((Bsx) + r * BK +                           \
                                  ((kk * 4 + quad) ^ (r & 7)) * 8);          \
      }                                                                      \
      _Pragma("unroll") for (int i = 0; i < 4; ++i)                          \
          _Pragma("unroll") for (int j = 0; j < 4; ++j)                      \
              acc[i][j] = __builtin_amdgcn_mfma_f32_16x16x32_bf16(           \
                  af[i], bfr[j], acc[i][j], 0, 0, 0);                        \
    }                                                                        \
  }

  // prologue: stage iter 0 into buf0; barrier drains it
  STAGE(As0, Bs0, 0);
  __syncthreads();

  // 8 trips x 2 iters (K=1024 -> 16 iters). One barrier per iter.
  for (int trip = 0; trip < 8; ++trip) {
    const int kt_e = trip * 128;
    // even iter: stage kt_e+64 -> buf1 BEFORE computing buf0
    STAGE(As1, Bs1, kt_e + 64);
    COMPUTE(As0, Bs0);
    __syncthreads();
    // odd iter: stage kt_e+128 -> buf0 BEFORE computing buf1
    if (trip < 7) {
      STAGE(As0, Bs0, kt_e + 128);
      COMPUTE(As1, Bs1);
      __syncthreads();
    } else {
      COMPUTE(As1, Bs1);
      // no barrier: epilogue T region overlaps only As0/Bs0 space, whose
      // last reads completed at the previous barrier; T is per-wave.
    }
  }
#undef STAGE
#undef COMPUTE

  // epilogue: MFMA C layout (col=l15, row=quad*4+r) -> per-wave LDS tile
  // (16 x 64, stride 68) -> full-line float4 stores. Same-wave ordering only.
  float* T = (float*)smem + wave * 1088;  // 16 rows x 68 stride
#pragma unroll
  for (int i = 0; i < 4; ++i) {
#pragma unroll
    for (int j = 0; j < 4; ++j) {
      const float bb = bias[bn + wn + j * 16 + l15];
#pragma unroll
      for (int r = 0; r < 4; ++r)
        T[(quad * 4 + r) * 68 + j * 16 + l15] = acc[i][j][r] + bb;
    }
#pragma unroll
    for (int p = 0; p < 4; ++p) {
      const int row = (lane >> 4) + 4 * p;
      const int ch = lane & 15;
      f32x4 v = *(const f32x4*)(T + row * 68 + ch * 4);
      *(f32x4*)(Out + (size_t)(bm + wm + i * 16 + row) * N + bn + wn +
                ch * 4) = v;
    }
  }
}

extern "C" void kernel_launch(void* const* d_in, const int* in_sizes, int n_in,
                              void* d_out, int out_size, void* d_ws,
                              size_t ws_size, hipStream_t stream) {
  // setup_inputs order: x, encoder_x, Wq, bq, Wk, bk, Wv, bv, Wo, bo
  const float* x  = (const float*)d_in[0];
  const float* Wv = (const float*)d_in[6];
  const float* bv = (const float*)d_in[7];
  const float* Wo = (const float*)d_in[8];
  const float* bo = (const float*)d_in[9];
  float* out = (float*)d_out;

  constexpr int D = 1024, NO = 1024;  // NO = H*QKV
  constexpr int M = 8192;             // B*L

  char* ws = (char*)d_ws;
  short* x_bf  = (short*)(ws);                  // 16 MB: x as bf16
  short* wt_bf = (short*)(ws + (16u << 20));    //  2 MB: 2048*(Wv@Wo)^T bf16
  float* biasc = (float*)(ws + (18u << 20));    //  4 KB: fused bias

  mid<<<4672, 256, 0, stream>>>(Wo, Wv, bv, bo, x, x_bf, wt_bf, biasc);
  gemm_main<<<(M / 128) * (NO / 128), 256, 0, stream>>>(
      x_bf, wt_bf, biasc, out, M, NO, D);
}

// Round 12
// 150.672 us; speedup vs baseline: 1.8821x; 1.0212x over previous
//
#include <hip/hip_runtime.h>
#include <stdint.h>

// ---------------------------------------------------------------------------
// CrossAttention_43061342110469 — algebraic reduction:
// einsum('bvhd,bhqk->bvhd', v, softmax(scores)) == v * L  (softmax rows sum
// to 1; summed over q gives L=2048). So out = 2048*(x @ Wv @ Wo) + const.
//
// R12: apply the R11-verified 2-phase dbuf skeleton to wgemm as well:
// Bsf x2 (16K) + Ts x2 (9K) = 50KB LDS, STAGE(t+1) issued BEFORE
// COMPUTE(t), one barrier/iter. Cast/bias branches and gemm_main are
// byte-identical to R11 (which measured 153.9 us).
//   K1 mid : [0,512) wgemm 2-phase, [512,576) bias, [576,4672) cast.
//   K2 gemm_main: x_bf @ Wt^T + biasc, both GLD16, 2-phase dbuf (R11).
// ---------------------------------------------------------------------------

typedef __attribute__((ext_vector_type(8))) short bf16x8;
typedef __attribute__((ext_vector_type(4))) float f32x4;

typedef __attribute__((address_space(1))) void as1_void;
typedef __attribute__((address_space(3))) void as3_void;
#define GLD16(g, s)                                                          \
  __builtin_amdgcn_global_load_lds((as1_void*)(g), (as3_void*)(s), 16, 0, 0)

__device__ __forceinline__ short f2bf(float f) {
  union { float f; uint32_t u; } v; v.f = f;
  uint32_t r = v.u + 0x7FFFu + ((v.u >> 16) & 1u);  // round-to-nearest-even
  return (short)(r >> 16);
}

// pack 8 fp32 -> bf16x8 (+0x8000, take high16 via v_perm)
__device__ __forceinline__ bf16x8 pack8(f32x4 a, f32x4 b) {
  union { f32x4 f; uint32_t u[4]; } x, y;
  x.f = a; y.f = b;
#pragma unroll
  for (int t = 0; t < 4; ++t) x.u[t] += 0x8000u;
#pragma unroll
  for (int t = 0; t < 4; ++t) y.u[t] += 0x8000u;
  union { bf16x8 v; uint32_t u[4]; } o;
  o.u[0] = __builtin_amdgcn_perm(x.u[1], x.u[0], 0x07060302);
  o.u[1] = __builtin_amdgcn_perm(x.u[3], x.u[2], 0x07060302);
  o.u[2] = __builtin_amdgcn_perm(y.u[1], y.u[0], 0x07060302);
  o.u[3] = __builtin_amdgcn_perm(y.u[3], y.u[2], 0x07060302);
  return o.v;
}

// ---- K1: [0,512) Wt = 2048*(Wv@Wo)^T (in-kernel Wo transpose, 2-phase);
//          [512,576) biasc; [576,4672) cast x fp32->bf16 (overlaps wgemm). --
__global__ __launch_bounds__(256) void mid(
    const float* __restrict__ Wo, const float* __restrict__ Wv,
    const float* __restrict__ bv, const float* __restrict__ bo,
    const float* __restrict__ x, short* __restrict__ x_bf,
    short* __restrict__ Wt, float* __restrict__ biasc) {
  constexpr int BK = 64, NW = 1024;
  __shared__ __align__(16) float Bsf0[64 * BK];  // 16 KB fp32 (Wv tile, ping)
  __shared__ __align__(16) float Bsf1[64 * BK];  // 16 KB fp32 (Wv tile, pong)
  __shared__ __align__(16) float Ts0[64 * 36];   //  9 KB fp32 (Wo^T, ping)
  __shared__ __align__(16) float Ts1[64 * 36];   //  9 KB fp32 (Wo^T, pong)
  const int b = blockIdx.x, tid = threadIdx.x;

  if (b >= 576) {  // ---- cast x: fp32 -> bf16, 8 elems/thread
    const int i = (b - 576) * 256 + tid;
    const float4* p = (const float4*)x;
    float4 a = p[2 * (size_t)i], c = p[2 * (size_t)i + 1];
    *(bf16x8*)(x_bf + 8 * (size_t)i) =
        pack8((f32x4){a.x, a.y, a.z, a.w}, (f32x4){c.x, c.y, c.z, c.w});
    return;
  }

  if (b >= 512) {  // ---- bias blocks
    float* red = Bsf0;
    const int b3 = b - 512;
    const int nx = tid & 15, ky = tid >> 4;
    const int n = b3 * 16 + nx;
    float s = 0.f;
    for (int k = ky; k < 1024; k += 16)
      s += bv[k] * Wo[(size_t)k * NW + n];
    red[tid] = s;
    __syncthreads();
#pragma unroll
    for (int st = 128; st >= 16; st >>= 1) {
      if (tid < st) red[tid] += red[tid + st];
      __syncthreads();
    }
    if (ky == 0) biasc[n] = 2048.0f * red[nx] + bo[n];
    return;
  }

  // ---- gemm blocks: bm = n-tile (Wo cols), bn = k-tile (Wv rows)
  const int lane = tid & 63, wave = tid >> 6;
  const int bm = (b >> 4) * 32, bn = (b & 15) * 64;
  const int wm = (wave & 1) * 16, wn = (wave >> 1) * 32;
  const int l15 = lane & 15, quad = lane >> 4;

  f32x4 acc[2];
  acc[0] = (f32x4){0.f, 0.f, 0.f, 0.f};
  acc[1] = (f32x4){0.f, 0.f, 0.f, 0.f};

  // B (fp32): 64 rows x 16 chunks(16B), 4/thread, XOR swizzle
  const int br = tid >> 4, bc4 = (tid & 15) ^ (br & 7);
  const float* pb = Wv + (size_t)(bn + br) * NW + bc4 * 4;
  // A (Wo transpose-stage): rows j = tid>>3 (+32), cols bm + (tid&7)*4
  const int ajr = tid >> 3, ac4 = (tid & 7) * 4;
  const float* pa = Wo + (size_t)ajr * NW + bm + ac4;

#define STAGEW(Tsx, Bsx, kt)                                                 \
  {                                                                          \
    float4 va = *(const float4*)(pa + (size_t)(kt)*NW);                      \
    float4 vb = *(const float4*)(pa + (size_t)((kt) + 32) * NW);             \
    _Pragma("unroll") for (int s = 0; s < 4; ++s)                            \
        GLD16(pb + (size_t)(16 * s) * NW + (kt), (Bsx) + tid * 4 + 1024 * s);\
    *(float4*)((Tsx) + ajr * 36 + ac4) = va;                                 \
    *(float4*)((Tsx) + (ajr + 32) * 36 + ac4) = vb;                          \
  }
#define COMPW(Tsx, Bsx)                                                      \
  {                                                                          \
    _Pragma("unroll") for (int kk = 0; kk < 2; ++kk) {                       \
      const float* tsp = (Tsx) + ((kk * 4 + quad) * 8) * 36 + wm + l15;      \
      float av[8];                                                           \
      _Pragma("unroll") for (int e = 0; e < 8; ++e) av[e] = tsp[e * 36];     \
      bf16x8 af = pack8((f32x4){av[0], av[1], av[2], av[3]},                 \
                        (f32x4){av[4], av[5], av[6], av[7]});                \
      _Pragma("unroll") for (int j = 0; j < 2; ++j) {                        \
        const int rn = wn + j * 16 + l15;                                    \
        const int c4 = kk * 8 + quad * 2;                                    \
        f32x4 u0 = *(const f32x4*)((Bsx) + (rn * 16 + (c4 ^ (rn & 7))) * 4); \
        f32x4 u1 =                                                           \
            *(const f32x4*)((Bsx) + (rn * 16 + ((c4 + 1) ^ (rn & 7))) * 4);  \
        acc[j] = __builtin_amdgcn_mfma_f32_16x16x32_bf16(af, pack8(u0, u1),  \
                                                         acc[j], 0, 0, 0);   \
      }                                                                      \
    }                                                                        \
  }

  // prologue: stage iter 0 into ping
  STAGEW(Ts0, Bsf0, 0);
  __syncthreads();

  // 8 trips x 2 iters (K=1024, BK=64 -> 16 iters). One barrier per iter.
  for (int trip = 0; trip < 8; ++trip) {
    const int kt_e = trip * 128;
    STAGEW(Ts1, Bsf1, kt_e + 64);   // stage t+1 BEFORE compute t
    COMPW(Ts0, Bsf0);
    __syncthreads();
    if (trip < 7) {
      STAGEW(Ts0, Bsf0, kt_e + 128);
      COMPW(Ts1, Bsf1);
      __syncthreads();
    } else {
      COMPW(Ts1, Bsf1);
    }
  }
#undef STAGEW
#undef COMPW

#pragma unroll
  for (int j = 0; j < 2; ++j) {
    const int col = bn + wn + j * 16 + l15;   // k-dim
    const int row0 = bm + wm + quad * 4;      // n-dim
#pragma unroll
    for (int r = 0; r < 4; ++r)
      Wt[(size_t)(row0 + r) * NW + col] = f2bf(2048.f * acc[j][r]);
  }
}

// ---- K2: out = x_bf @ Wt^T + biasc; 128x128, both GLD16, 2-phase dbuf -----
// (R11 verbatim — measured as part of 153.9 us)
__global__ __launch_bounds__(256) void gemm_main(
    const short* __restrict__ A, const short* __restrict__ Bt,
    const float* __restrict__ bias, float* __restrict__ Out,
    int M, int N, int K) {
  constexpr int BK = 64;
  __shared__ __align__(16) char smem[65536];  // As0,Bs0,As1,Bs1 (16K each)
  short* As0 = (short*)smem;
  short* Bs0 = (short*)(smem + 16384);
  short* As1 = (short*)(smem + 32768);
  short* Bs1 = (short*)(smem + 49152);
  const int tid = threadIdx.x, lane = tid & 63, wave = tid >> 6;
  const int b = blockIdx.x;
  const int bm = (b & 63) * 128;
  const int bn = (b >> 6) * 128;
  const int wm = (wave & 1) * 64, wn = (wave >> 1) * 64;
  const int l15 = lane & 15, quad = lane >> 4;

  f32x4 acc[4][4];
#pragma unroll
  for (int i = 0; i < 4; ++i)
#pragma unroll
    for (int j = 0; j < 4; ++j) acc[i][j] = (f32x4){0.f, 0.f, 0.f, 0.f};

  // staging with XOR chunk swizzle (LDS[row][c8] = global [row][c8^(row&7)])
  const int srow = tid >> 3, sc8 = (tid & 7) ^ (srow & 7);
  const short* pa = A + (size_t)(bm + srow) * K + sc8 * 8;
  const short* pb = Bt + (size_t)(bn + srow) * K + sc8 * 8;

#define STAGE(Asx, Bsx, kt)                                                  \
  {                                                                          \
    _Pragma("unroll") for (int s = 0; s < 4; ++s)                            \
        GLD16(pa + (size_t)(32 * s) * K + (kt), (Asx) + tid * 8 + 2048 * s); \
    _Pragma("unroll") for (int s = 0; s < 4; ++s)                            \
        GLD16(pb + (size_t)(32 * s) * K + (kt), (Bsx) + tid * 8 + 2048 * s); \
  }
#define COMPUTE(Asx, Bsx)                                                    \
  {                                                                          \
    _Pragma("unroll") for (int kk = 0; kk < 2; ++kk) {                       \
      bf16x8 af[4], bfr[4];                                                  \
      _Pragma("unroll") for (int i = 0; i < 4; ++i) {                        \
        const int r = wm + i * 16 + l15;                                     \
        af[i] = *(const bf16x8*)((Asx) + r * BK +                            \
                                 ((kk * 4 + quad) ^ (r & 7)) * 8);           \
      }                                                                      \
      _Pragma("unroll") for (int j = 0; j < 4; ++j) {                        \
        const int r = wn + j * 16 + l15;                                     \
        bfr[j] = *(const bf16x8*)((Bsx) + r * BK +                           \
                                  ((kk * 4 + quad) ^ (r & 7)) * 8);          \
      }                                                                      \
      _Pragma("unroll") for (int i = 0; i < 4; ++i)                          \
          _Pragma("unroll") for (int j = 0; j < 4; ++j)                      \
              acc[i][j] = __builtin_amdgcn_mfma_f32_16x16x32_bf16(           \
                  af[i], bfr[j], acc[i][j], 0, 0, 0);                        \
    }                                                                        \
  }

  // prologue: stage iter 0 into buf0; barrier drains it
  STAGE(As0, Bs0, 0);
  __syncthreads();

  // 8 trips x 2 iters (K=1024 -> 16 iters). One barrier per iter.
  for (int trip = 0; trip < 8; ++trip) {
    const int kt_e = trip * 128;
    STAGE(As1, Bs1, kt_e + 64);
    COMPUTE(As0, Bs0);
    __syncthreads();
    if (trip < 7) {
      STAGE(As0, Bs0, kt_e + 128);
      COMPUTE(As1, Bs1);
      __syncthreads();
    } else {
      COMPUTE(As1, Bs1);
      // no barrier: epilogue T region overlaps only As0/Bs0 space, whose
      // last reads completed at the previous barrier; T is per-wave.
    }
  }
#undef STAGE
#undef COMPUTE

  // epilogue: MFMA C layout (col=l15, row=quad*4+r) -> per-wave LDS tile
  // (16 x 64, stride 68) -> full-line float4 stores. Same-wave ordering only.
  float* T = (float*)smem + wave * 1088;  // 16 rows x 68 stride
#pragma unroll
  for (int i = 0; i < 4; ++i) {
#pragma unroll
    for (int j = 0; j < 4; ++j) {
      const float bb = bias[bn + wn + j * 16 + l15];
#pragma unroll
      for (int r = 0; r < 4; ++r)
        T[(quad * 4 + r) * 68 + j * 16 + l15] = acc[i][j][r] + bb;
    }
#pragma unroll
    for (int p = 0; p < 4; ++p) {
      const int row = (lane >> 4) + 4 * p;
      const int ch = lane & 15;
      f32x4 v = *(const f32x4*)(T + row * 68 + ch * 4);
      *(f32x4*)(Out + (size_t)(bm + wm + i * 16 + row) * N + bn + wn +
                ch * 4) = v;
    }
  }
}

extern "C" void kernel_launch(void* const* d_in, const int* in_sizes, int n_in,
                              void* d_out, int out_size, void* d_ws,
                              size_t ws_size, hipStream_t stream) {
  // setup_inputs order: x, encoder_x, Wq, bq, Wk, bk, Wv, bv, Wo, bo
  const float* x  = (const float*)d_in[0];
  const float* Wv = (const float*)d_in[6];
  const float* bv = (const float*)d_in[7];
  const float* Wo = (const float*)d_in[8];
  const float* bo = (const float*)d_in[9];
  float* out = (float*)d_out;

  constexpr int D = 1024, NO = 1024;  // NO = H*QKV
  constexpr int M = 8192;             // B*L

  char* ws = (char*)d_ws;
  short* x_bf  = (short*)(ws);                  // 16 MB: x as bf16
  short* wt_bf = (short*)(ws + (16u << 20));    //  2 MB: 2048*(Wv@Wo)^T bf16
  float* biasc = (float*)(ws + (18u << 20));    //  4 KB: fused bias

  mid<<<4672, 256, 0, stream>>>(Wo, Wv, bv, bo, x, x_bf, wt_bf, biasc);
  gemm_main<<<(M / 128) * (NO / 128), 256, 0, stream>>>(
      x_bf, wt_bf, biasc, out, M, NO, D);
}